// Round 4
// baseline (14997.804 us; speedup 1.0000x reference)
//
#include <hip/hip_runtime.h>

// ---------------------------------------------------------------------------
// 2-layer LSTM, T=1024, B=32, D=256, H=512. Inputs fp32, OUTPUT fp32.
//   1) pack_w: fp32 W_hh -> bf16 MFMA B-fragment order (register-resident
//      weights in the recurrence kernel).
//   2) gemm_xp: xp = A @ W^T (A fp32-permuted or bf16, W fp32; bf16 MFMA).
//   3) lstm_rec: persistent 32-wg kernel; wg owns 16 h-cols x 4 gates;
//      weights in VGPRs for all 1024 steps; cross-wg h exchange via global
//      double buffer + per-step flag barrier (release/acquire, agent scope).
// ---------------------------------------------------------------------------

typedef __bf16 bf16x8 __attribute__((ext_vector_type(8)));
typedef float  f32x4  __attribute__((ext_vector_type(4)));

#define MFMA16(a, b, c) __builtin_amdgcn_mfma_f32_16x16x32_bf16((a), (b), (c), 0, 0, 0)

__device__ __forceinline__ float fsigm(float x) { return 1.0f / (1.0f + __expf(-x)); }
__device__ __forceinline__ float ftanh(float x) {
    x = fminf(15.0f, fmaxf(-15.0f, x));
    float e = __expf(2.0f * x);
    return (e - 1.0f) / (e + 1.0f);
}

// ---------------------------------------------------------------------------
// Pack W_hh [2048][512] fp32 into per-(wg,wave,ktile) bf16 B-fragment order:
//   WB[((w*4+v)*16+kk)*512 + lane*8 + e] = bf16(W[grow][k0+e])
//   n = v*16 + (lane&15); grow = (n>>4)*512 + w*16 + (n&15); k0 = kk*32+(lane>>4)*8
// ---------------------------------------------------------------------------
__global__ void pack_w(const float* __restrict__ W0, const float* __restrict__ W1,
                       __bf16* __restrict__ WB0, __bf16* __restrict__ WB1) {
    int gtid = blockIdx.x * 256 + threadIdx.x;         // 0 .. 262143
    const float* W = (gtid < 131072) ? W0 : W1;
    __bf16* WB     = (gtid < 131072) ? WB0 : WB1;
    int tid  = gtid & 131071;
    int lane = tid & 63;
    int kk   = (tid >> 6) & 15;
    int v    = (tid >> 10) & 3;
    int w    = tid >> 12;                               // 0..31
    int n    = v * 16 + (lane & 15);
    int grow = (n >> 4) * 512 + w * 16 + (n & 15);
    int k0   = kk * 32 + (lane >> 4) * 8;
    const float* src = W + (size_t)grow * 512 + k0;
    bf16x8 val;
#pragma unroll
    for (int e = 0; e < 8; e++) val[e] = (__bf16)src[e];
    *(bf16x8*)(WB + (size_t)tid * 8) = val;
}

// ---------------------------------------------------------------------------
// xp[r][n] = sum_k Arow(r)[k] * W[n][k],  r = t*32+b (t-major), n in [0,2048)
// a_fp32_perm=1: A fp32, Arow(r) = A + ((r&31)*1024 + (r>>5))*K  (x is [B,T,D])
// a_fp32_perm=0: A bf16 row-major [32768][K]
// W fp32 [2048][K]. Tile: wg 128x128, wave 64x64 (4x4 of 16x16x32 MFMA).
// ---------------------------------------------------------------------------
__global__ __launch_bounds__(256, 2) void gemm_xp(const void* __restrict__ Av,
                                                  const float* __restrict__ W,
                                                  __bf16* __restrict__ out,
                                                  int K, int a_fp32_perm) {
    const int tid = threadIdx.x, lane = tid & 63, wv = tid >> 6;
    const int bm = blockIdx.x >> 4, bn = blockIdx.x & 15;
    const int m_base = bm * 128 + (wv & 1) * 64;
    const int n_base = bn * 128 + (wv >> 1) * 64;
    const int kq = (lane >> 4) * 8;
    const int rl = lane & 15;

    f32x4 acc[4][4];
#pragma unroll
    for (int i = 0; i < 4; i++)
#pragma unroll
        for (int j = 0; j < 4; j++) acc[i][j] = (f32x4){0.f, 0.f, 0.f, 0.f};

    const int nk = K >> 5;
    for (int kk = 0; kk < nk; kk++) {
        int k0 = kk * 32 + kq;
        bf16x8 af[4], bfr[4];
#pragma unroll
        for (int mt = 0; mt < 4; mt++) {
            int row = m_base + mt * 16 + rl;
            if (a_fp32_perm) {
                const float* A = (const float*)Av;
                const float* ap = A + (size_t)((row & 31) * 1024 + (row >> 5)) * K + k0;
#pragma unroll
                for (int e = 0; e < 8; e++) af[mt][e] = (__bf16)ap[e];
            } else {
                const __bf16* A = (const __bf16*)Av;
                af[mt] = *(const bf16x8*)(A + (size_t)row * K + k0);
            }
        }
#pragma unroll
        for (int nt = 0; nt < 4; nt++) {
            int n = n_base + nt * 16 + rl;
            const float* wp = W + (size_t)n * K + k0;
#pragma unroll
            for (int e = 0; e < 8; e++) bfr[nt][e] = (__bf16)wp[e];
        }
#pragma unroll
        for (int mt = 0; mt < 4; mt++)
#pragma unroll
            for (int nt = 0; nt < 4; nt++)
                acc[mt][nt] = MFMA16(af[mt], bfr[nt], acc[mt][nt]);
    }

    const int rq = (lane >> 4) * 4;
#pragma unroll
    for (int mt = 0; mt < 4; mt++)
#pragma unroll
        for (int nt = 0; nt < 4; nt++)
#pragma unroll
            for (int r = 0; r < 4; r++) {
                int row = m_base + mt * 16 + rq + r;
                int col = n_base + nt * 16 + rl;
                out[(size_t)row * 2048 + col] = (__bf16)acc[mt][nt][r];
            }
}

// ---------------------------------------------------------------------------
// Persistent recurrence. grid = 32 wgs x 256 thr. wg w owns j in [w*16,w*16+16)
// for all 4 gates. Weights in VGPRs (16 x bf16x8 per lane). Per step:
// A-frags (full h, 32x512 bf16) from global double buffer -> 32 MFMAs/wave ->
// gates via LDS -> elementwise (c fp32 in regs) -> h bf16 to global ->
// flag-array barrier (release store, 32-lane poll, agent acquire fence).
// layer0 writes hs0 (bf16, internal); layer1 writes out (fp32 [B][T][H]).
// h_n / c_n written fp32.
// ---------------------------------------------------------------------------
__global__ __launch_bounds__(256, 1) void lstm_rec(
    const __bf16* __restrict__ xp,    // [32768][2048] bf16, row = t*32+b
    const __bf16* __restrict__ WB,    // packed weights, 2 MB
    const float* __restrict__ bias,   // [2048] fp32
    __bf16* __restrict__ hbuf,        // [2][32][512] double buffer (zeroed)
    __bf16* __restrict__ hs0_bf,      // layer0 only: hs0[t*32+b][512] bf16
    float* __restrict__ out_f32,      // layer1 only: out[b][t][512] fp32
    float* __restrict__ hn_out,       // [32][512] fp32
    float* __restrict__ cn_out,       // [32][512] fp32
    int* flags,                       // [1024][32] zeroed
    int layer) {
    const int tid  = threadIdx.x;
    const int w    = blockIdx.x;   // 0..31
    const int lane = tid & 63;
    const int wv   = tid >> 6;     // wave 0..3

    __shared__ float g_lds[32 * 68];  // gates [32 b][64 cols], +4 pad

    // --- weights resident in registers for all 1024 steps ---
    bf16x8 wreg[16];
    {
        const __bf16* wb = WB + (size_t)(w * 4 + wv) * 16 * 512 + lane * 8;
#pragma unroll
        for (int kk = 0; kk < 16; kk++) wreg[kk] = *(const bf16x8*)(wb + kk * 512);
    }

    // --- elementwise mapping: thread -> (b0,j) and (b0+16,j) ---
    const int b0 = tid >> 4;       // 0..15
    const int jl = tid & 15;
    const int j  = w * 16 + jl;    // global h column
    float bsv[4];
#pragma unroll
    for (int g = 0; g < 4; g++) bsv[g] = bias[g * 512 + j];
    float cc[2] = {0.f, 0.f};

    const int aoff = (lane & 15) * 512 + (lane >> 4) * 8;  // A-frag lane offset

    // prefetch xp[t=0]
    __bf16 xcur[8], xnxt[8];
    {
        const __bf16* xr = xp + (size_t)w * 16 + jl;
#pragma unroll
        for (int g = 0; g < 4; g++) {
            xcur[g]     = xr[(size_t)b0 * 2048 + g * 512];
            xcur[4 + g] = xr[(size_t)(b0 + 16) * 2048 + g * 512];
        }
    }

    for (int t = 0; t < 1024; t++) {
        // prefetch xp[t+1] (independent of h; hides HBM latency)
        {
            int tn = (t < 1023) ? t + 1 : 1023;
            const __bf16* xr = xp + (size_t)tn * 32 * 2048 + w * 16 + jl;
#pragma unroll
            for (int g = 0; g < 4; g++) {
                xnxt[g]     = xr[(size_t)b0 * 2048 + g * 512];
                xnxt[4 + g] = xr[(size_t)(b0 + 16) * 2048 + g * 512];
            }
        }

        // --- MFMA: gates_pre[32 b][64 cols] = h @ Wslice^T ---
        const __bf16* hc = hbuf + (size_t)(t & 1) * 32 * 512;
        f32x4 acc0 = (f32x4){0.f, 0.f, 0.f, 0.f};
        f32x4 acc1 = (f32x4){0.f, 0.f, 0.f, 0.f};
#pragma unroll
        for (int kk = 0; kk < 16; kk++) {
            bf16x8 a0 = *(const bf16x8*)(hc + aoff + kk * 32);
            bf16x8 a1 = *(const bf16x8*)(hc + 16 * 512 + aoff + kk * 32);
            acc0 = MFMA16(a0, wreg[kk], acc0);
            acc1 = MFMA16(a1, wreg[kk], acc1);
        }
        // C frag: col = lane&15, row = (lane>>4)*4 + reg
        {
            int col   = wv * 16 + (lane & 15);
            int rbase = (lane >> 4) * 4;
#pragma unroll
            for (int r = 0; r < 4; r++) {
                g_lds[(rbase + r) * 68 + col]      = acc0[r];
                g_lds[(16 + rbase + r) * 68 + col] = acc1[r];
            }
        }
        __syncthreads();

        // --- elementwise gate math ---
        __bf16* hnx = hbuf + (size_t)((t + 1) & 1) * 32 * 512;
#pragma unroll
        for (int p = 0; p < 2; p++) {
            int bb = b0 + p * 16;
            float ig = g_lds[bb * 68 + jl]      + (float)xcur[p * 4 + 0] + bsv[0];
            float fg = g_lds[bb * 68 + 16 + jl] + (float)xcur[p * 4 + 1] + bsv[1];
            float gg = g_lds[bb * 68 + 32 + jl] + (float)xcur[p * 4 + 2] + bsv[2];
            float og = g_lds[bb * 68 + 48 + jl] + (float)xcur[p * 4 + 3] + bsv[3];
            float iv = fsigm(ig), fv = fsigm(fg), gv = ftanh(gg), ov = fsigm(og);
            cc[p] = fv * cc[p] + iv * gv;
            float hv = ov * ftanh(cc[p]);
            __bf16 hb = (__bf16)hv;
            hnx[bb * 512 + j] = hb;
            if (layer == 0)
                hs0_bf[((size_t)t * 32 + bb) * 512 + j] = hb;  // hs0 bf16, row-major
            else
                out_f32[(size_t)bb * 524288 + (size_t)t * 512 + j] = hv;  // fp32 out[b][t][j]
            if (t == 1023) {
                hn_out[bb * 512 + j] = hv;      // fp32
                cn_out[bb * 512 + j] = cc[p];   // fp32, unrounded
            }
        }

        if (t < 1023) {
            __syncthreads();  // drains all h stores + LDS reads done
            if (tid == 0)
                __hip_atomic_store(&flags[t * 32 + w], 1, __ATOMIC_RELEASE,
                                   __HIP_MEMORY_SCOPE_AGENT);
            if (tid < 32) {
                while (__hip_atomic_load(&flags[t * 32 + tid], __ATOMIC_RELAXED,
                                         __HIP_MEMORY_SCOPE_AGENT) == 0) {}
            }
            __builtin_amdgcn_fence(__ATOMIC_ACQUIRE, "agent");
            __syncthreads();
        }
#pragma unroll
        for (int g = 0; g < 8; g++) xcur[g] = xnxt[g];
    }
}

// ---------------------------------------------------------------------------
extern "C" void kernel_launch(void* const* d_in, const int* in_sizes, int n_in,
                              void* d_out, int out_size, void* d_ws, size_t ws_size,
                              hipStream_t stream) {
    (void)in_sizes; (void)n_in; (void)out_size; (void)ws_size;
    const float* x    = (const float*)d_in[0];  // [32][1024][256] fp32
    const float* Wih0 = (const float*)d_in[1];  // [2048][256] fp32
    const float* b0   = (const float*)d_in[2];  // [2048] fp32
    const float* Whh0 = (const float*)d_in[3];  // [2048][512] fp32
    const float* Wih1 = (const float*)d_in[4];  // [2048][512] fp32
    const float* b1   = (const float*)d_in[5];  // [2048] fp32
    const float* Whh1 = (const float*)d_in[6];  // [2048][512] fp32
    float* dout = (float*)d_out;  // fp32: out(16777216) | h_n(2*16384) | c_n(2*16384)

    char* wsb = (char*)d_ws;
    int*    flags = (int*)wsb;                                   // 256 KB (2 layers)
    __bf16* hbuf0 = (__bf16*)(wsb + (256 << 10));                // 64 KB
    __bf16* hbuf1 = (__bf16*)(wsb + (320 << 10));                // 64 KB
    __bf16* WB0   = (__bf16*)(wsb + (384 << 10));                // 2 MB
    __bf16* WB1   = (__bf16*)(wsb + (384 << 10) + (2 << 20));    // 2 MB
    __bf16* hs0   = (__bf16*)(wsb + (384 << 10) + (4 << 20));    // 32 MB
    __bf16* xpb   = (__bf16*)(wsb + (384 << 10) + (36 << 20));   // 128 MB (xp0/xp1 shared)

    // zero flags + both h double-buffers (contiguous 384 KB)
    (void)hipMemsetAsync(wsb, 0, 384 << 10, stream);

    pack_w<<<dim3(1024), dim3(256), 0, stream>>>(Whh0, Whh1, WB0, WB1);

    // layer 0: xp0 = x @ Wih0^T  (K=256, fp32 A, permuted rows)
    gemm_xp<<<dim3(4096), dim3(256), 0, stream>>>((const void*)x, Wih0, xpb, 256, 1);
    lstm_rec<<<dim3(32), dim3(256), 0, stream>>>(
        xpb, WB0, b0, hbuf0, hs0, (float*)nullptr,
        dout + 16777216, dout + 16777216 + 32768, flags, 0);

    // layer 1: xp1 = hs0 @ Wih1^T  (K=512, bf16 A row-major)
    gemm_xp<<<dim3(4096), dim3(256), 0, stream>>>((const void*)hs0, Wih1, xpb, 512, 0);
    lstm_rec<<<dim3(32), dim3(256), 0, stream>>>(
        xpb, WB1, b1, hbuf1, (__bf16*)nullptr, dout,
        dout + 16777216 + 16384, dout + 16777216 + 32768 + 16384, flags + 32768, 1);
}